// Round 1
// baseline (405.951 us; speedup 1.0000x reference)
//
#include <hip/hip_runtime.h>

typedef _Float16 half8 __attribute__((ext_vector_type(8)));
typedef _Float16 half4 __attribute__((ext_vector_type(4)));
typedef float floatx4 __attribute__((ext_vector_type(4)));

constexpr int Bn = 32768, Kn = 4096, Dn = 256;
constexpr int BM = 128, BN = 128;
constexpr int NI = Kn / BN;   // 32 N-tiles
constexpr int NCH = NI * 4;   // 128 chunks of 64 d's

// Exact fp32 ||e_k||^2 — one wave per code.
__global__ void esq_kernel(const float* __restrict__ w, float* __restrict__ esq) {
    int code = blockIdx.x * 4 + (threadIdx.x >> 6);
    int lane = threadIdx.x & 63;
    float4 v = *reinterpret_cast<const float4*>(w + (size_t)code * Dn + lane * 4);
    float s = v.x * v.x + v.y * v.y + v.z * v.z + v.w * v.w;
    #pragma unroll
    for (int off = 32; off; off >>= 1) s += __shfl_xor(s, off);
    if (lane == 0) esq[code] = s;
}

// Fused: fp16-split (hi+lo) 3-pass MFMA cross-product, on-the-fly argmin,
// gather epilogue. 8 waves, BM=128 rows/block, A resident in registers.
__launch_bounds__(512, 2)
__global__ void vq_kernel(const float* __restrict__ z, const float* __restrict__ w,
                          const float* __restrict__ esq,
                          float* __restrict__ out0, float* __restrict__ out1,
                          float* __restrict__ out2) {
    __shared__ char smem[65536];  // 2 buffers x (whi 16KB + wlo 16KB)
    const int tid = threadIdx.x;
    const int wave = tid >> 6, lane = tid & 63;
    const int lg = lane >> 4, lc = lane & 15;
    const int rowBase = blockIdx.x * BM;
    const int waveRow = rowBase + wave * 16;

    // ---- A (z rows) -> registers as f16 hi/lo fragments ----
    // lane lc = row, group lg picks d-quarter; 8 k-steps of 32 d.
    half8 a_hi[8], a_lo[8];
    {
        const float* zr = z + (size_t)(waveRow + lc) * Dn;
        #pragma unroll
        for (int ks = 0; ks < 8; ++ks) {
            int d0 = ks * 32 + lg * 8;
            float4 f0 = *reinterpret_cast<const float4*>(zr + d0);
            float4 f1 = *reinterpret_cast<const float4*>(zr + d0 + 4);
            float fv[8] = {f0.x, f0.y, f0.z, f0.w, f1.x, f1.y, f1.z, f1.w};
            #pragma unroll
            for (int j = 0; j < 8; ++j) {
                _Float16 h = (_Float16)fv[j];
                a_hi[ks][j] = h;
                a_lo[ks][j] = (_Float16)(fv[j] - (float)h);
            }
        }
    }

    // staging role: 4 threads per code, each 16 consecutive floats
    const int scode = tid >> 2, sp = tid & 3;
    float4 r0, r1, r2, r3;

    auto issue = [&](int c) {  // issue global loads for chunk c (T14 early)
        const float* wp = w + (size_t)((c >> 2) * BN + scode) * Dn + (c & 3) * 64 + sp * 16;
        r0 = *reinterpret_cast<const float4*>(wp);
        r1 = *reinterpret_cast<const float4*>(wp + 4);
        r2 = *reinterpret_cast<const float4*>(wp + 8);
        r3 = *reinterpret_cast<const float4*>(wp + 12);
    };
    auto writeLds = [&](int c) {  // convert + swizzled LDS write (T14 late)
        char* base = smem + (c & 1) * 32768;
        float fv[16] = {r0.x, r0.y, r0.z, r0.w, r1.x, r1.y, r1.z, r1.w,
                        r2.x, r2.y, r2.z, r2.w, r3.x, r3.y, r3.z, r3.w};
        #pragma unroll
        for (int q = 0; q < 4; ++q) {
            half4 h, l;
            #pragma unroll
            for (int j = 0; j < 4; ++j) {
                float x = fv[q * 4 + j];
                _Float16 hh = (_Float16)x;
                h[j] = hh;
                l[j] = (_Float16)(x - (float)hh);
            }
            int dloc = sp * 16 + q * 4;
            int off = scode * 128 + ((dloc * 2) ^ ((scode & 7) << 4));  // G4 swizzle
            *reinterpret_cast<half4*>(base + off) = h;
            *reinterpret_cast<half4*>(base + 16384 + off) = l;
        }
    };

    floatx4 acc[8];
    float rbv[4] = {3.4e38f, 3.4e38f, 3.4e38f, 3.4e38f};
    int rbi[4] = {0, 0, 0, 0};

    issue(0);
    writeLds(0);
    __syncthreads();

    for (int ni = 0; ni < NI; ++ni) {
        #pragma unroll
        for (int nf = 0; nf < 8; ++nf) acc[nf] = (floatx4){0.f, 0.f, 0.f, 0.f};

        #pragma unroll
        for (int kc = 0; kc < 4; ++kc) {  // unrolled: a_hi[ks] stays in regs (rule #20)
            const int c = ni * 4 + kc;
            const bool pf = (c + 1) < NCH;
            if (pf) issue(c + 1);
            char* base = smem + (c & 1) * 32768;
            #pragma unroll
            for (int ks2 = 0; ks2 < 2; ++ks2) {
                const int ks = kc * 2 + ks2;
                const int dloc = ks2 * 32 + lg * 8;
                #pragma unroll
                for (int nf = 0; nf < 8; ++nf) {
                    const int code = nf * 16 + lc;
                    const int off = code * 128 + ((dloc * 2) ^ ((code & 7) << 4));
                    half8 bh = *reinterpret_cast<const half8*>(base + off);
                    half8 bl = *reinterpret_cast<const half8*>(base + 16384 + off);
                    // fp16x3 emulated-fp32: hi*hi + hi*lo + lo*hi into same acc
                    acc[nf] = __builtin_amdgcn_mfma_f32_16x16x32_f16(a_hi[ks], bh, acc[nf], 0, 0, 0);
                    acc[nf] = __builtin_amdgcn_mfma_f32_16x16x32_f16(a_hi[ks], bl, acc[nf], 0, 0, 0);
                    acc[nf] = __builtin_amdgcn_mfma_f32_16x16x32_f16(a_lo[ks], bh, acc[nf], 0, 0, 0);
                }
            }
            if (pf) writeLds(c + 1);
            __syncthreads();
        }

        // ---- epilogue: score = esq - 2*cross ; argmin with first-occurrence ties
        const int n0 = ni * BN;
        float ev[8];
        #pragma unroll
        for (int nf = 0; nf < 8; ++nf) ev[nf] = esq[n0 + nf * 16 + lc];
        #pragma unroll
        for (int i = 0; i < 4; ++i) {  // C layout: col=lane&15, row=lg*4+i (m89)
            float bv = fmaf(-2.f, acc[0][i], ev[0]);
            int bi = n0 + lc;
            #pragma unroll
            for (int nf = 1; nf < 8; ++nf) {
                float s = fmaf(-2.f, acc[nf][i], ev[nf]);
                int idx = n0 + nf * 16 + lc;
                if (s < bv) { bv = s; bi = idx; }  // idx ascending: strict < = first occurrence
            }
            #pragma unroll
            for (int off = 1; off < 16; off <<= 1) {  // reduce across the 16-lane group
                float ov = __shfl_xor(bv, off);
                int oi = __shfl_xor(bi, off);
                if (ov < bv || (ov == bv && oi < bi)) { bv = ov; bi = oi; }
            }
            if (bv < rbv[i] || (bv == rbv[i] && bi < rbi[i])) { rbv[i] = bv; rbi[i] = bi; }
        }
    }

    __syncthreads();
    int* idxArr = reinterpret_cast<int*>(smem);  // reuse LDS after K-loop
    if (lc == 0) {
        #pragma unroll
        for (int i = 0; i < 4; ++i) idxArr[wave * 16 + lg * 4 + i] = rbi[i];
    }
    __syncthreads();

    // ---- gather: out0 = z + (q - z) (ref's exact expression), out1 = q, out2 = idx
    {
        const int r = tid >> 2, p = tid & 3;
        const int gRow = rowBase + r;
        const int idx = idxArr[r];
        const float* wr = w + (size_t)idx * Dn + p * 64;
        const float* zr = z + (size_t)gRow * Dn + p * 64;
        float* o0 = out0 + (size_t)gRow * Dn + p * 64;
        float* o1 = out1 + (size_t)gRow * Dn + p * 64;
        #pragma unroll
        for (int q = 0; q < 16; ++q) {
            float4 wv = *reinterpret_cast<const float4*>(wr + q * 4);
            float4 zv = *reinterpret_cast<const float4*>(zr + q * 4);
            *reinterpret_cast<float4*>(o1 + q * 4) = wv;
            float4 sg;
            sg.x = zv.x + (wv.x - zv.x);
            sg.y = zv.y + (wv.y - zv.y);
            sg.z = zv.z + (wv.z - zv.z);
            sg.w = zv.w + (wv.w - zv.w);
            *reinterpret_cast<float4*>(o0 + q * 4) = sg;
        }
        if (p == 0) out2[gRow] = (float)idx;
    }
}

extern "C" void kernel_launch(void* const* d_in, const int* in_sizes, int n_in,
                              void* d_out, int out_size, void* d_ws, size_t ws_size,
                              hipStream_t stream) {
    (void)in_sizes; (void)n_in; (void)out_size;
    const float* z = (const float*)d_in[0];
    const float* w = (const float*)d_in[1];
    float* esq = (float*)d_ws;  // 16 KB; ws_size is always >= this
    (void)ws_size;
    float* out0 = (float*)d_out;
    float* out1 = out0 + (size_t)Bn * Dn;
    float* out2 = out1 + (size_t)Bn * Dn;

    esq_kernel<<<Kn / 4, 256, 0, stream>>>(w, esq);
    vq_kernel<<<Bn / BM, 512, 0, stream>>>(z, w, esq, out0, out1, out2);
}

// Round 2
// 291.253 us; speedup vs baseline: 1.3938x; 1.3938x over previous
//
#include <hip/hip_runtime.h>

typedef _Float16 half8 __attribute__((ext_vector_type(8)));
typedef _Float16 half4 __attribute__((ext_vector_type(4)));
typedef float floatx16 __attribute__((ext_vector_type(16)));

constexpr int Bn = 32768, Kn = 4096, Dn = 256;
constexpr int BM = 128;            // rows per block
constexpr int BNS = 64;            // codes per ni step
constexpr int NI = Kn / BNS;       // 64 steps
constexpr int NCH = NI * 4;        // 256 chunks (64 codes x 64 k x {hi,lo})
constexpr size_t W16_PLANE = (size_t)Kn * Dn * 2;   // 2 MB per plane

// ---- prep: exact fp32 ||e||^2 + f16 hi/lo codebook planes ----
__global__ void prep_kernel(const float* __restrict__ w, float* __restrict__ esq,
                            _Float16* __restrict__ w16) {
    int code = blockIdx.x * 4 + (threadIdx.x >> 6);
    int lane = threadIdx.x & 63;
    float4 v = *reinterpret_cast<const float4*>(w + (size_t)code * Dn + lane * 4);
    float s = v.x * v.x + v.y * v.y + v.z * v.z + v.w * v.w;
    #pragma unroll
    for (int off = 32; off; off >>= 1) s += __shfl_xor(s, off);
    if (lane == 0) esq[code] = s;
    float fv[4] = {v.x, v.y, v.z, v.w};
    half4 h, l;
    #pragma unroll
    for (int j = 0; j < 4; ++j) {
        _Float16 hh = (_Float16)fv[j];
        h[j] = hh;
        l[j] = (_Float16)(fv[j] - (float)hh);
    }
    _Float16* hi = w16 + (size_t)code * Dn + lane * 4;
    *reinterpret_cast<half4*>(hi) = h;
    *reinterpret_cast<half4*>(hi + (size_t)Kn * Dn) = l;
}

#define GLDS(gsrc, ldsoff)                                                        \
    __builtin_amdgcn_global_load_lds(                                             \
        (const __attribute__((address_space(1))) unsigned int*)(const void*)(gsrc),\
        (__attribute__((address_space(3))) unsigned int*)(void*)(smem + (ldsoff)), \
        16, 0, 0)

// LDS map: buf 4x16384 = [0,65536) | esq_s [65536,81920) | comb [81920,83968) | idxF [83968,84480)
__launch_bounds__(512, 2)
__global__ void vq_kernel(const float* __restrict__ z, const float* __restrict__ w,
                          const float* __restrict__ esq, const _Float16* __restrict__ w16,
                          float* __restrict__ out0, float* __restrict__ out1,
                          float* __restrict__ out2) {
    __shared__ char smem[84480];
    const int tid = threadIdx.x;
    const int wv_ = tid >> 6, l = tid & 63;
    const int mw = wv_ >> 1, nw = wv_ & 1;     // 4 M-waves x 2 N-waves
    const int lh = l >> 5, ll = l & 31;
    const int blkRow = blockIdx.x * BM;

    // esq -> LDS
    float* esq_s = reinterpret_cast<float*>(smem + 65536);
    #pragma unroll
    for (int j = 0; j < 8; ++j) esq_s[j * 512 + tid] = esq[j * 512 + tid];

    // A (32 z-rows per wave) -> registers, f16 hi/lo split. lane: row=ll, k=ks*16+lh*8+j
    half8 a_hi[16], a_lo[16];
    {
        const float* zr = z + (size_t)(blkRow + mw * 32 + ll) * Dn + lh * 8;
        #pragma unroll
        for (int ks = 0; ks < 16; ++ks) {
            float4 f0 = *reinterpret_cast<const float4*>(zr + ks * 16);
            float4 f1 = *reinterpret_cast<const float4*>(zr + ks * 16 + 4);
            float fv[8] = {f0.x, f0.y, f0.z, f0.w, f1.x, f1.y, f1.z, f1.w};
            #pragma unroll
            for (int j = 0; j < 8; ++j) {
                _Float16 h = (_Float16)fv[j];
                a_hi[ks][j] = h;
                a_lo[ks][j] = (_Float16)(fv[j] - (float)h);
            }
        }
    }

    // DMA source (per-lane, XOR-pre-swizzled so linear LDS dest lands swizzled; rule #21)
    const int sc = tid >> 3;                                   // local code 0..63
    const int se = ((tid & 7) * 16) ^ ((sc & 7) << 4);
    const char* srcH = reinterpret_cast<const char*>(w16) + (size_t)sc * 512 + se;
    const char* srcL = srcH + W16_PLANE;

    // ds_read addresses: col c=nw*32+ll, addr = c*128 + ((ks*32+lh*16) ^ ((c&7)<<4))
    int vks[4];
    {
        const int c_loc = nw * 32 + ll;
        const int swz = (c_loc & 7) << 4;
        #pragma unroll
        for (int ks = 0; ks < 4; ++ks) vks[ks] = c_loc * 128 + ((ks * 32 + lh * 16) ^ swz);
    }

    float rbv[16];
    int rbi[16];
    #pragma unroll
    for (int q = 0; q < 16; ++q) { rbv[q] = 3.4e38f; rbi[q] = 0; }

    __syncthreads();   // drain prologue (esq ds_writes + z loads) before counted-vmcnt regime

    // prologue DMA: chunks 0 (buf0) and 1 (buf1)
    GLDS(srcH, 0 + wv_ * 1024);
    GLDS(srcL, 0 + 8192 + wv_ * 1024);
    GLDS(srcH + 128, 16384 + wv_ * 1024);
    GLDS(srcL + 128, 16384 + 8192 + wv_ * 1024);

    for (int ni = 0; ni < NI; ++ni) {
        floatx16 acc = {};
        #pragma unroll
        for (int kc = 0; kc < 4; ++kc) {   // chunk c = ni*4+kc; buffer = kc (compile-time)
            if (ni == NI - 1 && kc == 3) asm volatile("s_waitcnt vmcnt(0)" ::: "memory");
            else                         asm volatile("s_waitcnt vmcnt(2)" ::: "memory");
            __builtin_amdgcn_s_barrier();
            asm volatile("" ::: "memory");
            {   // prefetch chunk c+2 into buffer (kc+2)&3 (read last at chunk c-2: safe)
                const int c2 = ni * 4 + kc + 2;
                if (c2 < NCH) {
                    const size_t off2 = (size_t)(c2 >> 2) * 32768 + (size_t)(c2 & 3) * 128;
                    const int b2 = ((kc + 2) & 3) * 16384;
                    GLDS(srcH + off2, b2 + wv_ * 1024);
                    GLDS(srcL + off2, b2 + 8192 + wv_ * 1024);
                }
            }
            __builtin_amdgcn_s_setprio(1);
            #pragma unroll
            for (int ks = 0; ks < 4; ++ks) {
                const half8 bh = *reinterpret_cast<const half8*>(smem + kc * 16384 + vks[ks]);
                const half8 bl = *reinterpret_cast<const half8*>(smem + kc * 16384 + 8192 + vks[ks]);
                const half8 ah = a_hi[kc * 4 + ks];
                const half8 al = a_lo[kc * 4 + ks];
                // fp16x3 emulated-fp32 cross: hi*hi + hi*lo + lo*hi into fp32 acc
                acc = __builtin_amdgcn_mfma_f32_32x32x16_f16(ah, bh, acc, 0, 0, 0);
                acc = __builtin_amdgcn_mfma_f32_32x32x16_f16(ah, bl, acc, 0, 0, 0);
                acc = __builtin_amdgcn_mfma_f32_32x32x16_f16(al, bh, acc, 0, 0, 0);
            }
            __builtin_amdgcn_s_setprio(0);
        }
        // per-ni argmin update: lane holds 16 rows x 1 col; col = ni*64 + nw*32 + ll
        const int col = ni * 64 + nw * 32 + ll;
        const float e = esq_s[col];
        #pragma unroll
        for (int q = 0; q < 16; ++q) {
            float v = fmaf(-2.f, acc[q], e);
            if (v < rbv[q]) { rbv[q] = v; rbi[q] = col; }   // ni ascending: strict < = first occurrence
        }
    }

    // cross-lane argmin over 32 cols (shfl_xor stays within each 32-lane half; rows differ by lh)
    #pragma unroll
    for (int off = 1; off < 32; off <<= 1) {
        #pragma unroll
        for (int q = 0; q < 16; ++q) {
            float ov = __shfl_xor(rbv[q], off);
            int oi = __shfl_xor(rbi[q], off);
            if (ov < rbv[q] || (ov == rbv[q] && oi < rbi[q])) { rbv[q] = ov; rbi[q] = oi; }
        }
    }

    int2* comb = reinterpret_cast<int2*>(smem + 81920);   // [128 rows][2 nw]
    if (ll == 0) {
        #pragma unroll
        for (int q = 0; q < 16; ++q) {
            int row = mw * 32 + (q & 3) + 8 * (q >> 2) + 4 * lh;   // m74 C-layout
            comb[row * 2 + nw] = make_int2(__float_as_int(rbv[q]), rbi[q]);
        }
    }
    __syncthreads();
    int* idxF = reinterpret_cast<int*>(smem + 83968);
    if (tid < 128) {
        int2 c0 = comb[tid * 2], c1 = comb[tid * 2 + 1];
        float v0 = __int_as_float(c0.x), v1 = __int_as_float(c1.x);
        idxF[tid] = (v1 < v0 || (v1 == v0 && c1.y < c0.y)) ? c1.y : c0.y;
    }
    __syncthreads();

    // gather epilogue: out0 = z + (q - z) (ref's exact expr), out1 = q, out2 = idx
    {
        const int r = tid >> 2, p4 = tid & 3;
        const int gRow = blkRow + r;
        const int idx = idxF[r];
        const float* wr = w + (size_t)idx * Dn + p4 * 64;
        const float* zr = z + (size_t)gRow * Dn + p4 * 64;
        float* o0 = out0 + (size_t)gRow * Dn + p4 * 64;
        float* o1 = out1 + (size_t)gRow * Dn + p4 * 64;
        #pragma unroll
        for (int q = 0; q < 16; ++q) {
            float4 wq = *reinterpret_cast<const float4*>(wr + q * 4);
            float4 zq = *reinterpret_cast<const float4*>(zr + q * 4);
            *reinterpret_cast<float4*>(o1 + q * 4) = wq;
            float4 sg;
            sg.x = zq.x + (wq.x - zq.x);
            sg.y = zq.y + (wq.y - zq.y);
            sg.z = zq.z + (wq.z - zq.z);
            sg.w = zq.w + (wq.w - zq.w);
            *reinterpret_cast<float4*>(o0 + q * 4) = sg;
        }
        if (p4 == 0) out2[gRow] = (float)idx;
    }
}

extern "C" void kernel_launch(void* const* d_in, const int* in_sizes, int n_in,
                              void* d_out, int out_size, void* d_ws, size_t ws_size,
                              hipStream_t stream) {
    (void)in_sizes; (void)n_in; (void)out_size; (void)ws_size;
    const float* z = (const float*)d_in[0];
    const float* w = (const float*)d_in[1];
    float* esq = (float*)d_ws;                                  // 16 KB
    _Float16* w16 = (_Float16*)((char*)d_ws + 16384);           // 4 MB (hi plane + lo plane)
    float* out0 = (float*)d_out;
    float* out1 = out0 + (size_t)Bn * Dn;
    float* out2 = out1 + (size_t)Bn * Dn;

    prep_kernel<<<Kn / 4, 256, 0, stream>>>(w, esq, w16);
    vq_kernel<<<Bn / BM, 512, 0, stream>>>(z, w, esq, w16, out0, out1, out2);
}